// Round 2
// baseline (160.432 us; speedup 1.0000x reference)
//
#include <hip/hip_runtime.h>

#define CAS(a, b) { float _t = fminf(a, b); (b) = fmaxf(a, b); (a) = _t; }

__device__ __forceinline__ void sort5(float& a0, float& a1, float& a2, float& a3, float& a4) {
    // optimal 9-comparator 5-sort
    CAS(a0, a1); CAS(a3, a4); CAS(a2, a4); CAS(a2, a3);
    CAS(a0, a3); CAS(a0, a2); CAS(a1, a4); CAS(a1, a3); CAS(a1, a2);
}

#define TILE_W 32
#define TILE_H 8
#define HALO   2
#define LDS_W  (TILE_W + 2 * HALO)   // 36
#define LDS_H  (TILE_H + 2 * HALO)   // 12
#define IMG_W  1024
#define IMG_H  1024

__global__ __launch_bounds__(256, 4)
void median5x5_kernel(const float* __restrict__ in, float* __restrict__ out) {
    __shared__ float tile[LDS_H][LDS_W];          // raw input tile + halo (1728 B)
    __shared__ float scol[5][TILE_H][LDS_W];      // sorted columns, per output row (5760 B)

    const int tx  = threadIdx.x;            // 0..31
    const int ty  = threadIdx.y;            // 0..7
    const int tid = ty * TILE_W + tx;
    const int x0  = blockIdx.x * TILE_W;
    const int y0  = blockIdx.y * TILE_H;
    const float* plane = in + (size_t)blockIdx.z * (IMG_W * IMG_H);

    // ---- phase A: cooperative halo load with zero padding ----
    #pragma unroll
    for (int idx = tid; idx < LDS_H * LDS_W; idx += 256) {
        int r  = idx / LDS_W;
        int c  = idx - r * LDS_W;
        int gy = y0 - HALO + r;
        int gx = x0 - HALO + c;
        float v = 0.0f;
        if ((unsigned)gx < (unsigned)IMG_W && (unsigned)gy < (unsigned)IMG_H)
            v = plane[gy * IMG_W + gx];
        tile[r][c] = v;
    }
    __syncthreads();

    // ---- phase B: shared column sorts ----
    // output row ty uses input tile rows ty..ty+4; 36 columns per row, 32 threads:
    // each thread sorts column tx, and threads tx<4 also sort column 32+tx.
    #pragma unroll
    for (int c = tx; c < LDS_W; c += TILE_W) {
        float c0 = tile[ty + 0][c];
        float c1 = tile[ty + 1][c];
        float c2 = tile[ty + 2][c];
        float c3 = tile[ty + 3][c];
        float c4 = tile[ty + 4][c];
        sort5(c0, c1, c2, c3, c4);
        scol[0][ty][c] = c0;
        scol[1][ty][c] = c1;
        scol[2][ty][c] = c2;
        scol[3][ty][c] = c3;
        scol[4][ty][c] = c4;
    }
    __syncthreads();

    // ---- phase C: gather column-sorted 5x5 window ----
    // w[i][j] = i-th smallest of column (x0+tx-2+j) over rows (y-2..y+2)
    float w[5][5];
    #pragma unroll
    for (int i = 0; i < 5; ++i)
        #pragma unroll
        for (int j = 0; j < 5; ++j)
            w[i][j] = scol[i][ty][tx + j];

    // ---- phase D: sort rows (columns stay sorted -> doubly sorted matrix) ----
    #pragma unroll
    for (int i = 0; i < 5; ++i)
        sort5(w[i][0], w[i][1], w[i][2], w[i][3], w[i][4]);

    // ---- phase E: 13-candidate selection on the doubly-sorted matrix ----
    // row0:{a03,a04} row1:{a12,a13,a14} row2:{a21,a22,a23} row3:{a30,a31,a32} row4:{a40,a41}
    // median of 25 == rank-7 of these 13.

    // A = merge(row0-cands, row1-cands) -> sorted 5 (uses a03<=a13, a04<=a14)
    float p = w[0][3], q = w[0][4];
    float r_ = w[1][2], s = w[1][3], t = w[1][4];
    CAS(p, r_); CAS(q, r_); CAS(r_, s);          // A = [p, q, r_, s, t]

    // C = merge(row3-cands, row4-cands) -> sorted 5 (uses a30<=a40, a31<=a41)
    float x = w[3][0], y = w[3][1], z = w[3][2];
    float m = w[4][0], n = w[4][1];
    CAS(z, n); CAS(z, m); CAS(y, z);             // C = [x, y, z, m, n]

    // bitonic half-cleaner between A and reversed C:
    // L = 5 smallest of A∪C, U = 5 largest
    CAS(p, n); CAS(q, m); CAS(r_, z); CAS(s, y); CAS(t, x);
    // L = [p,q,r_,s,t] (bitonic), U = [n,m,z,y,x] (bitonic)

    // top-2 (sorted) of L  -> ranks 4,5 of A∪C
    float M01 = fmaxf(p, q),  m01 = fminf(p, q);
    float M23 = fmaxf(r_, s), m23 = fminf(r_, s);
    float max4 = fmaxf(M01, M23);
    float sec4 = fmaxf(fminf(M01, M23), fmaxf(m01, m23));
    float l2 = fmaxf(max4, t);
    float l1 = fmaxf(fminf(max4, t), sec4);

    // bottom-2 (sorted) of U -> ranks 6,7 of A∪C
    float mn01 = fminf(n, m),  Mx01 = fmaxf(n, m);
    float mn23 = fminf(z, y),  Mx23 = fmaxf(z, y);
    float min4  = fminf(mn01, mn23);
    float sec4b = fminf(fmaxf(mn01, mn23), fminf(Mx01, Mx23));
    float u1 = fminf(min4, x);
    float u2 = fminf(fmaxf(min4, x), sec4b);

    // final: median-of-7 of sorted G=[l1,l2,u1,u2] and sorted H=row2 cands,
    // via pruned Batcher merge(4,3)
    float h0 = w[2][1], h1 = w[2][2], h2 = w[2][3];
    float E2 = fmaxf(fmaxf(l1, h0), fminf(u1, h2));
    float O1 = __builtin_amdgcn_fmed3f(l2, u2, h1);
    float med = fminf(E2, O1);

    out[(size_t)blockIdx.z * (IMG_W * IMG_H) + (size_t)(y0 + ty) * IMG_W + (x0 + tx)] = med;
}

extern "C" void kernel_launch(void* const* d_in, const int* in_sizes, int n_in,
                              void* d_out, int out_size, void* d_ws, size_t ws_size,
                              hipStream_t stream) {
    const float* in  = (const float*)d_in[0];
    float*       out = (float*)d_out;
    dim3 block(TILE_W, TILE_H, 1);                      // 256 threads
    dim3 grid(IMG_W / TILE_W, IMG_H / TILE_H, 12);      // 32 x 128 x (B*C)
    hipLaunchKernelGGL(median5x5_kernel, grid, block, 0, stream, in, out);
}

// Round 4
// 133.276 us; speedup vs baseline: 1.2038x; 1.2038x over previous
//
#include <hip/hip_runtime.h>

#define CAS(a, b) { float _t = fminf(a, b); (b) = fmaxf(a, b); (a) = _t; }

#define IMG    1024
#define TW     64            // output tile width (2 px per thread * 32 threads)
#define TH     8             // output tile height
#define RAW_W  72            // raw tile: covers gx in [x0-4, x0+68)
#define RAW_H  12            // covers gy in [y0-2, y0+10)

__device__ __forceinline__ void sort5(float& a0, float& a1, float& a2, float& a3, float& a4) {
    // optimal 9-comparator 5-sort
    CAS(a0, a1); CAS(a3, a4); CAS(a2, a4); CAS(a2, a3);
    CAS(a0, a3); CAS(a0, a2); CAS(a1, a4); CAS(a1, a3); CAS(a1, a2);
}

// rank-7 of the 13 candidates of a doubly-sorted 5x5 (HW-verified in v2, absmax=0)
__device__ __forceinline__ float tail13(float a03, float a04,
                                        float a12, float a13, float a14,
                                        float a21, float a22, float a23,
                                        float a30, float a31, float a32,
                                        float a40, float a41) {
    float p = a03, q = a04, r_ = a12, s = a13, t = a14;
    CAS(p, r_); CAS(q, r_); CAS(r_, s);          // A = [p,q,r_,s,t] sorted
    float x = a30, y = a31, z = a32, m = a40, n = a41;
    CAS(z, n); CAS(z, m); CAS(y, z);             // C = [x,y,z,m,n] sorted
    // bitonic half-cleaner
    CAS(p, n); CAS(q, m); CAS(r_, z); CAS(s, y); CAS(t, x);
    // top-2 of L
    float M01 = fmaxf(p, q),  m01 = fminf(p, q);
    float M23 = fmaxf(r_, s), m23 = fminf(r_, s);
    float max4 = fmaxf(M01, M23);
    float sec4 = fmaxf(fminf(M01, M23), fmaxf(m01, m23));
    float l2 = fmaxf(max4, t);
    float l1 = fmaxf(fminf(max4, t), sec4);
    // bottom-2 of U
    float mn01 = fminf(n, m),  Mx01 = fmaxf(n, m);
    float mn23 = fminf(z, y),  Mx23 = fmaxf(z, y);
    float min4  = fminf(mn01, mn23);
    float sec4b = fminf(fmaxf(mn01, mn23), fminf(Mx01, Mx23));
    float u1 = fminf(min4, x);
    float u2 = fminf(fmaxf(min4, x), sec4b);
    // pruned Batcher merge(4,3)
    float E2 = fmaxf(fmaxf(l1, a21), fminf(u1, a23));
    float O1 = __builtin_amdgcn_fmed3f(l2, u2, a22);
    return fminf(E2, O1);
}

__global__ __launch_bounds__(256, 4)
void median5x5_kernel(const float* __restrict__ in, float* __restrict__ out) {
    __shared__ float tile[RAW_H][RAW_W];         // 3456 B
    __shared__ float scol[5][TH][RAW_W];         // 11520 B

    const int tx  = threadIdx.x;                 // 0..31
    const int ty  = threadIdx.y;                 // 0..7
    const int tid = ty * 32 + tx;
    const int x0  = blockIdx.x * TW;
    const int y0  = blockIdx.y * TH;
    const float* plane = in + (size_t)blockIdx.z * (IMG * IMG);

    // ---- phase A: vectorized halo load (float4 chunks are all-in or all-out) ----
    if (tid < RAW_H * (RAW_W / 4)) {             // 12 * 18 = 216 tasks
        int r   = tid / 18;
        int k   = tid - r * 18;
        int gy  = y0 - 2 + r;
        int gx0 = x0 - 4 + 4 * k;
        float4 v = make_float4(0.f, 0.f, 0.f, 0.f);
        if ((unsigned)gy < IMG && (unsigned)gx0 < IMG)
            v = *(const float4*)(plane + (size_t)gy * IMG + gx0);
        *(float4*)&tile[r][4 * k] = v;
    }
    __syncthreads();

    // ---- phase B: shared column sorts (cols 2..69 used; col c = gx - x0 + 4) ----
#define SORTCOL(c) { \
        float c0 = tile[ty + 0][c], c1 = tile[ty + 1][c], c2 = tile[ty + 2][c], \
              c3 = tile[ty + 3][c], c4 = tile[ty + 4][c]; \
        sort5(c0, c1, c2, c3, c4); \
        scol[0][ty][c] = c0; scol[1][ty][c] = c1; scol[2][ty][c] = c2; \
        scol[3][ty][c] = c3; scol[4][ty][c] = c4; }
    SORTCOL(tx + 2);
    SORTCOL(tx + 34);
    if (tx < 4) SORTCOL(tx + 66);
#undef SORTCOL
    __syncthreads();

    // ---- phase C/D: per rank-row, read 6 shared columns, sort4 middle, extract
    //      order statistics for both pixels (X = x0+2tx, X+1) ----
    const int cb = 2 * tx + 2;                   // leftmost col of union window
    float v0, v1, v2, v3, v4, v5, m0, m1, m2, m3, t1, t2;

#define LOADROW(i) { \
        const float* rp = &scol[i][ty][cb]; \
        float2 ua = *(const float2*)rp; \
        float2 ub = *(const float2*)(rp + 2); \
        float2 uc = *(const float2*)(rp + 4); \
        v0 = ua.x; v1 = ua.y; v2 = ub.x; v3 = ub.y; v4 = uc.x; v5 = uc.y; \
        m0 = v1; m1 = v2; m2 = v3; m3 = v4; \
        CAS(m0, m1); CAS(m2, m3); CAS(m0, m2); CAS(m1, m3); CAS(m1, m2); }

    // row 0: top-2 (ranks 3,4)
    LOADROW(0);
    float A03, A04, B03, B04;
    A04 = fmaxf(m3, v0); A03 = fmaxf(fminf(m3, v0), m2);
    B04 = fmaxf(m3, v5); B03 = fmaxf(fminf(m3, v5), m2);

    // row 1: top-3 (ranks 2,3,4)
    LOADROW(1);
    float A12, A13, A14, B12, B13, B14;
    A14 = fmaxf(m3, v0); t1 = fminf(m3, v0); A13 = fmaxf(m2, t1); t2 = fminf(m2, t1); A12 = fmaxf(m1, t2);
    B14 = fmaxf(m3, v5); t1 = fminf(m3, v5); B13 = fmaxf(m2, t1); t2 = fminf(m2, t1); B12 = fmaxf(m1, t2);

    // row 2: middle-3 (ranks 1,2,3)
    LOADROW(2);
    float A21, A22, A23, B21, B22, B23;
    A21 = fmaxf(m0, fminf(m1, v0));
    A22 = __builtin_amdgcn_fmed3f(m1, m2, v0);
    A23 = fminf(m3, fmaxf(m2, v0));
    B21 = fmaxf(m0, fminf(m1, v5));
    B22 = __builtin_amdgcn_fmed3f(m1, m2, v5);
    B23 = fminf(m3, fmaxf(m2, v5));

    // row 3: bottom-3 (ranks 0,1,2)
    LOADROW(3);
    float A30, A31, A32, B30, B31, B32;
    A30 = fminf(m0, v0); t1 = fmaxf(m0, v0); A31 = fminf(m1, t1); t2 = fmaxf(m1, t1); A32 = fminf(m2, t2);
    B30 = fminf(m0, v5); t1 = fmaxf(m0, v5); B31 = fminf(m1, t1); t2 = fmaxf(m1, t1); B32 = fminf(m2, t2);

    // row 4: bottom-2 (ranks 0,1)
    LOADROW(4);
    float A40, A41, B40, B41;
    A40 = fminf(m0, v0); A41 = fminf(fmaxf(m0, v0), m1);
    B40 = fminf(m0, v5); B41 = fminf(fmaxf(m0, v5), m1);
#undef LOADROW

    float medA = tail13(A03, A04, A12, A13, A14, A21, A22, A23, A30, A31, A32, A40, A41);
    float medB = tail13(B03, B04, B12, B13, B14, B21, B22, B23, B30, B31, B32, B40, B41);

    float2 o; o.x = medA; o.y = medB;
    *(float2*)(out + (size_t)blockIdx.z * (IMG * IMG) + (size_t)(y0 + ty) * IMG + x0 + 2 * tx) = o;
}

extern "C" void kernel_launch(void* const* d_in, const int* in_sizes, int n_in,
                              void* d_out, int out_size, void* d_ws, size_t ws_size,
                              hipStream_t stream) {
    const float* in  = (const float*)d_in[0];
    float*       out = (float*)d_out;
    dim3 block(32, TH, 1);                       // 256 threads
    dim3 grid(IMG / TW, IMG / TH, 12);           // 16 x 128 x (B*C)
    hipLaunchKernelGGL(median5x5_kernel, grid, block, 0, stream, in, out);
}